// Round 2
// baseline (1250.513 us; speedup 1.0000x reference)
//
#include <hip/hip_runtime.h>
#include <hip/hip_bf16.h>

#define B_ 8
#define C_ 96
#define H_ 256
#define W_ 256
#define HW_ (H_*W_)
#define EPSV 1e-5f

// dw-chain tile
#define TH 16
#define TW 64
#define HR (TH+6)      // 22 halo rows
#define HC (TW+6)      // 70 halo cols
#define HSTR (HC+2)    // 72 padded LDS stride
#define NHALO (HR*HC)  // 1540

// ---------------------------------------------------------------------------
// Kernel 0: per-pixel LayerNorm stats (mean, rstd) over channel dim.
// ---------------------------------------------------------------------------
__global__ __launch_bounds__(256) void k_stats(const float* __restrict__ fea,
                                               float2* __restrict__ stats) {
    int p = blockIdx.x * 256 + threadIdx.x;      // pixel index in [0, B*HW)
    int b = p >> 16;                              // HW_ = 65536
    int r = p & (HW_ - 1);
    const float* pp = fea + (size_t)b * C_ * HW_ + r;
    float s = 0.f, sq = 0.f;
#pragma unroll 8
    for (int c = 0; c < C_; ++c) {
        float v = pp[(size_t)c * HW_];
        s += v; sq += v * v;
    }
    float mu  = s * (1.0f / C_);
    float var = sq * (1.0f / C_) - mu * mu;
    stats[p] = make_float2(mu, rsqrtf(var + EPSV));
}

// ---------------------------------------------------------------------------
// Kernel 1: fused LN-apply + dw3x3 + dw1x5 + dw5x1 per channel, tiled in LDS.
// Intermediate convs are masked to 0 outside the image (the reference
// zero-pads BETWEEN convs; bias must not leak into the padding).
// ---------------------------------------------------------------------------
__global__ __launch_bounds__(256) void k_dw(
    const float* __restrict__ fea,
    const float* __restrict__ gamma, const float* __restrict__ beta,
    const float* __restrict__ w1, const float* __restrict__ b1,
    const float* __restrict__ w2, const float* __restrict__ b2,
    const float* __restrict__ w3, const float* __restrict__ b3,
    const float2* __restrict__ stats, _Float16* __restrict__ y3out)
{
    __shared__ float2 sst[NHALO];
    __shared__ float xs [HR * HSTR];
    __shared__ float y1b[HR * HSTR];
    __shared__ float y2b[HR * HSTR];

    const int tid = threadIdx.x;
    const int bw0 = blockIdx.x * TW;
    const int bh0 = blockIdx.y * TH;
    const int b   = blockIdx.z;

    // Stage LN stats for the halo into LDS (once per block).
    for (int p = tid; p < NHALO; p += 256) {
        int rr = p / HC, cc = p - rr * HC;
        int gh = bh0 - 3 + rr, gw = bw0 - 3 + cc;
        float2 st = make_float2(0.f, 0.f);
        if ((unsigned)gh < H_ && (unsigned)gw < W_)
            st = stats[((size_t)b * H_ + gh) * W_ + gw];
        sst[p] = st;
    }
    __syncthreads();

#pragma unroll 1
    for (int c = 0; c < C_; ++c) {
        const float g  = gamma[c], bt = beta[c];
        float w1v[9], w2v[5], w3v[5];
#pragma unroll
        for (int i = 0; i < 9; ++i) w1v[i] = w1[c * 9 + i];
#pragma unroll
        for (int i = 0; i < 5; ++i) w2v[i] = w2[c * 5 + i];
#pragma unroll
        for (int i = 0; i < 5; ++i) w3v[i] = w3[c * 5 + i];
        const float bb1 = b1[c], bb2 = b2[c], bb3 = b3[c];
        const float* feac = fea + ((size_t)b * C_ + c) * HW_;

        // x = LN(fea) on the full halo (zeros outside the image = conv1 pad)
        for (int p = tid; p < NHALO; p += 256) {
            int rr = p / HC, cc = p - rr * HC;
            int gh = bh0 - 3 + rr, gw = bw0 - 3 + cc;
            float v = 0.f;
            if ((unsigned)gh < H_ && (unsigned)gw < W_) {
                float2 st = sst[p];
                v = (feac[gh * W_ + gw] - st.x) * st.y * g + bt;
            }
            xs[rr * HSTR + cc] = v;
        }
        __syncthreads();

        // y1 = 3x3 (rows 1..20, cols 1..68); ZERO outside image (conv2 pad)
        for (int p = tid; p < 20 * 68; p += 256) {
            int rr = 1 + p / 68, cc = 1 + p - (p / 68) * 68;
            float s = bb1;
#pragma unroll
            for (int i = 0; i < 3; ++i)
#pragma unroll
                for (int j = 0; j < 3; ++j)
                    s += w1v[i * 3 + j] * xs[(rr - 1 + i) * HSTR + (cc - 1 + j)];
            int gh = bh0 - 3 + rr, gw = bw0 - 3 + cc;
            bool in = ((unsigned)gh < H_) && ((unsigned)gw < W_);
            y1b[rr * HSTR + cc] = in ? s : 0.f;
        }
        __syncthreads();

        // y2 = 1x5 (rows 1..20, cols 3..66); cols are always interior,
        // rows can be outside -> ZERO there (conv3 pad)
        for (int p = tid; p < 20 * 64; p += 256) {
            int rr = 1 + (p >> 6), cc = 3 + (p & 63);
            float s = bb2;
#pragma unroll
            for (int j = 0; j < 5; ++j)
                s += w2v[j] * y1b[rr * HSTR + cc - 2 + j];
            int gh = bh0 - 3 + rr;
            y2b[rr * HSTR + cc] = ((unsigned)gh < H_) ? s : 0.f;
        }
        __syncthreads();

        // y3 = 5x1 (interior 16x64), store fp16
        for (int p = tid; p < TH * TW; p += 256) {
            int rr = 3 + (p >> 6), cc = 3 + (p & 63);
            float s = bb3;
#pragma unroll
            for (int i = 0; i < 5; ++i)
                s += w3v[i] * y2b[(rr - 2 + i) * HSTR + cc];
            int gh = bh0 + rr - 3, gw = bw0 + cc - 3;
            y3out[(((size_t)b * C_ + c) * H_ + gh) * W_ + gw] = (_Float16)s;
        }
        __syncthreads();
    }
}

// ---------------------------------------------------------------------------
// Kernel 2: pointwise 96x96 matvec per pixel + gate with recomputed-x (fp32).
// ---------------------------------------------------------------------------
__global__ __launch_bounds__(256) void k_pw(
    const float* __restrict__ fea,
    const float* __restrict__ gamma, const float* __restrict__ beta,
    const float* __restrict__ pw,
    const _Float16* __restrict__ y3, const float2* __restrict__ stats,
    float* __restrict__ out)
{
    const int w = threadIdx.x;
    const int h = blockIdx.x;
    const int b = blockIdx.y;

    float y[C_];
#pragma unroll
    for (int k = 0; k < C_; ++k)
        y[k] = (float)y3[(((size_t)b * C_ + k) * H_ + h) * W_ + w];

    const float2 st = stats[((size_t)b * H_ + h) * W_ + w];

#pragma unroll 1
    for (int c = 0; c < C_; ++c) {
        float a0 = 0.f, a1 = 0.f, a2 = 0.f, a3 = 0.f;
        const float* pwr = pw + c * C_;
#pragma unroll
        for (int k = 0; k < C_; k += 4) {
            a0 += pwr[k + 0] * y[k + 0];
            a1 += pwr[k + 1] * y[k + 1];
            a2 += pwr[k + 2] * y[k + 2];
            a3 += pwr[k + 3] * y[k + 3];
        }
        float acc = (a0 + a1) + (a2 + a3);
        size_t idx = (((size_t)b * C_ + c) * H_ + h) * W_ + w;
        float xv = (fea[idx] - st.x) * st.y * gamma[c] + beta[c];
        out[idx] = acc * xv;
    }
}

extern "C" void kernel_launch(void* const* d_in, const int* in_sizes, int n_in,
                              void* d_out, int out_size, void* d_ws, size_t ws_size,
                              hipStream_t stream) {
    const float* fea   = (const float*)d_in[0];
    const float* gamma = (const float*)d_in[1];
    const float* beta  = (const float*)d_in[2];
    const float* w1    = (const float*)d_in[3];
    const float* b1    = (const float*)d_in[4];
    const float* w2    = (const float*)d_in[5];
    const float* b2    = (const float*)d_in[6];
    const float* w3    = (const float*)d_in[7];
    const float* b3    = (const float*)d_in[8];
    const float* pw    = (const float*)d_in[9];
    float* out = (float*)d_out;

    _Float16* y3buf = (_Float16*)d_ws;                                    // 100.7 MB
    float2*   stats = (float2*)((char*)d_ws + (size_t)B_ * C_ * HW_ * 2); // +4.2 MB

    k_stats<<<dim3(B_ * HW_ / 256), 256, 0, stream>>>(fea, stats);
    k_dw<<<dim3(W_ / TW, H_ / TH, B_), 256, 0, stream>>>(
        fea, gamma, beta, w1, b1, w2, b2, w3, b3, stats, y3buf);
    k_pw<<<dim3(H_, B_), 256, 0, stream>>>(fea, gamma, beta, pw, y3buf, stats, out);
}

// Round 3
// 785.987 us; speedup vs baseline: 1.5910x; 1.5910x over previous
//
#include <hip/hip_runtime.h>
#include <hip/hip_bf16.h>

#define B_ 8
#define C_ 96
#define H_ 256
#define W_ 256
#define HW_ (H_*W_)
#define EPSV 1e-5f

typedef _Float16 f16x8 __attribute__((ext_vector_type(8)));
typedef float    f32x4 __attribute__((ext_vector_type(4)));

// ---------------------------------------------------------------------------
// K1: per-pixel LN stats, 2 pixels/thread via float2 loads.
// ---------------------------------------------------------------------------
__global__ __launch_bounds__(256) void k_stats(const float* __restrict__ fea,
                                               float4* __restrict__ stats4) {
    int p2 = blockIdx.x * 256 + threadIdx.x;   // pixel-pair index
    int b  = p2 >> 15;                          // 32768 pairs per batch
    int r  = (p2 & 32767) * 2;
    const float* pp = fea + (size_t)b * C_ * HW_ + r;
    float s0 = 0.f, q0 = 0.f, s1 = 0.f, q1 = 0.f;
#pragma unroll 8
    for (int c = 0; c < C_; ++c) {
        float2 v = *(const float2*)(pp + (size_t)c * HW_);
        s0 += v.x; q0 += v.x * v.x;
        s1 += v.y; q1 += v.y * v.y;
    }
    float mu0 = s0 * (1.0f / C_), mu1 = s1 * (1.0f / C_);
    float rs0 = rsqrtf(q0 * (1.0f / C_) - mu0 * mu0 + EPSV);
    float rs1 = rsqrtf(q1 * (1.0f / C_) - mu1 * mu1 + EPSV);
    stats4[p2] = make_float4(mu0, rs0, mu1, rs1);
}

// ---------------------------------------------------------------------------
// K2: one (channel, 64x64 tile) per block. LN-apply + 3x3 + 1x5 + 5x1 in LDS
// with aligned float4 window reads. 3 barriers total. y3 stored fp16 NCHW.
// ---------------------------------------------------------------------------
#define XS 72   // LDS row stride (floats)

__global__ __launch_bounds__(256) void k_dw(
    const float* __restrict__ fea, const float2* __restrict__ stats,
    const float* __restrict__ gamma, const float* __restrict__ beta,
    const float* __restrict__ w1, const float* __restrict__ b1,
    const float* __restrict__ w2, const float* __restrict__ b2,
    const float* __restrict__ w3, const float* __restrict__ b3,
    _Float16* __restrict__ y3out)
{
    __shared__ float xs [70 * XS];   // x tile (rows 0..69 ~ gh-3.., cols 0..69)
    __shared__ float y1b[70 * XS];   // y1 (valid rows/cols 1..68); cols 0,69..71 zeroed
    float* y2b = xs;                 // y2 overlays xs (valid rows 1..68, cols 2..69)

    const int tid = threadIdx.x;
    const int bw0 = blockIdx.x * 64;
    const int bh0 = blockIdx.y * 64;
    const int z   = blockIdx.z;
    const int c   = z % C_;
    const int b   = z / C_;

    // one-time zero of y1b columns never written by conv1 but read by conv2
    if (tid < 70) {
        y1b[tid * XS + 0]  = 0.f; y1b[tid * XS + 69] = 0.f;
        y1b[tid * XS + 70] = 0.f; y1b[tid * XS + 71] = 0.f;
    }

    const float g  = gamma[c], bt = beta[c];
    float w1v[9], w2v[5], w3v[5];
#pragma unroll
    for (int i = 0; i < 9; ++i) w1v[i] = w1[c * 9 + i];
#pragma unroll
    for (int i = 0; i < 5; ++i) w2v[i] = w2[c * 5 + i];
#pragma unroll
    for (int i = 0; i < 5; ++i) w3v[i] = w3[c * 5 + i];
    const float bb1 = b1[c], bb2 = b2[c], bb3 = b3[c];
    const float*  feac = fea   + ((size_t)b * C_ + c) * HW_;
    const float2* stb  = stats + (size_t)b * HW_;

    // stage x = LN(fea) over the 70x70 halo (0 outside image)
    for (int p = tid; p < 70 * 70; p += 256) {
        int r  = p / 70, cc = p - r * 70;
        int gh = bh0 - 3 + r, gw = bw0 - 3 + cc;
        float v = 0.f;
        if ((unsigned)gh < H_ && (unsigned)gw < W_) {
            float2 st = stb[(gh << 8) + gw];
            v = (feac[(gh << 8) + gw] - st.x) * st.y * g + bt;
        }
        xs[r * XS + cc] = v;
    }
    __syncthreads();

    // conv1 3x3: rows 1..68, col-groups of 4 (17 groups), zero outside image
    for (int t = tid; t < 68 * 17; t += 256) {
        int r1 = 1 + t / 17, cg = t - 17 * (t / 17);
        int cb = 4 * cg;                        // window col base
        float wnd[3][8];
#pragma unroll
        for (int dr = 0; dr < 3; ++dr) {
            float4 a = *(const float4*)&xs[(r1 - 1 + dr) * XS + cb];
            float4 d = *(const float4*)&xs[(r1 - 1 + dr) * XS + cb + 4];
            wnd[dr][0]=a.x; wnd[dr][1]=a.y; wnd[dr][2]=a.z; wnd[dr][3]=a.w;
            wnd[dr][4]=d.x; wnd[dr][5]=d.y; wnd[dr][6]=d.z; wnd[dr][7]=d.w;
        }
        int gh = bh0 - 3 + r1;
        bool rin = (unsigned)gh < H_;
#pragma unroll
        for (int i2 = 0; i2 < 4; ++i2) {
            int c1 = cb + 1 + i2;
            float s = bb1;
#pragma unroll
            for (int dr = 0; dr < 3; ++dr)
#pragma unroll
                for (int dj = 0; dj < 3; ++dj)
                    s += w1v[dr * 3 + dj] * wnd[dr][i2 + dj];
            int gw = bw0 - 3 + c1;
            y1b[r1 * XS + c1] = (rin && (unsigned)gw < W_) ? s : 0.f;
        }
    }
    __syncthreads();

    // conv2 1x5: rows 1..68, outputs cols 4g+2..4g+5 (g=0..16) from y1 cols 4g..4g+7
    for (int t = tid; t < 68 * 17; t += 256) {
        int r2 = 1 + t / 17, gq = t - 17 * (t / 17);
        int cb = 4 * gq;
        float4 a = *(const float4*)&y1b[r2 * XS + cb];
        float4 d = *(const float4*)&y1b[r2 * XS + cb + 4];
        float wnd[8] = {a.x,a.y,a.z,a.w,d.x,d.y,d.z,d.w};
        int gh = bh0 - 3 + r2;
        bool rin = (unsigned)gh < H_;
#pragma unroll
        for (int i2 = 0; i2 < 4; ++i2) {
            int cc = cb + 2 + i2;
            float s = bb2;
#pragma unroll
            for (int j = 0; j < 5; ++j) s += w2v[j] * wnd[i2 + j];
            int gw = bw0 - 3 + cc;
            y2b[r2 * XS + cc] = (rin && (unsigned)gw < W_) ? s : 0.f;
        }
    }
    __syncthreads();

    // conv3 5x1: 64 rows x 8 groups of 8 cols; outputs cc = 8g+3..8g+10
    for (int t = tid; t < 64 * 8; t += 256) {
        int rt = t >> 3, gq = t & 7;
        int cb = 8 * gq;
        float accv[8];
#pragma unroll
        for (int i = 0; i < 8; ++i) accv[i] = bb3;
#pragma unroll
        for (int dr = 0; dr < 5; ++dr) {
            int rr = rt + 1 + dr;                // y2 rows rt+1..rt+5
            float4 a = *(const float4*)&y2b[rr * XS + cb];
            float4 d = *(const float4*)&y2b[rr * XS + cb + 4];
            float4 e = *(const float4*)&y2b[rr * XS + cb + 8];
            float wnd[12] = {a.x,a.y,a.z,a.w,d.x,d.y,d.z,d.w,e.x,e.y,e.z,e.w};
#pragma unroll
            for (int i = 0; i < 8; ++i) accv[i] += w3v[dr] * wnd[3 + i];
        }
        union { uint4 q; _Float16 h[8]; } pk;
#pragma unroll
        for (int i = 0; i < 8; ++i) pk.h[i] = (_Float16)accv[i];
        size_t idx = ((size_t)b * C_ + c) * HW_ + ((bh0 + rt) << 8) + bw0 + cb;
        *(uint4*)&y3out[idx] = pk.q;
    }
}

// ---------------------------------------------------------------------------
// K3: pointwise 96x96 as fp16 MFMA GEMM per 256-pixel block + fp32 gate.
// A = pw (LDS, fp16, stride 104), B = y3 fragments gathered from global.
// D frag: col = lane&15 (pixel), row = (lane>>4)*4 + r (out channel).
// ---------------------------------------------------------------------------
#define PWS 104   // pw LDS row stride in f16

__global__ __launch_bounds__(256) void k_pw(
    const _Float16* __restrict__ y3, const float* __restrict__ fea,
    const float2* __restrict__ stats,
    const float* __restrict__ gamma, const float* __restrict__ beta,
    const float* __restrict__ pw, float* __restrict__ out)
{
    __shared__ _Float16 pwl[C_ * PWS];
    const int tid = threadIdx.x;

    // stage pw fp32 -> fp16 LDS (9216 elems = 18 iters * 256 thr * 2)
#pragma unroll 1
    for (int i = 0; i < 18; ++i) {
        int f = (i * 256 + tid) * 2;
        float2 v = *(const float2*)(pw + f);
        int c = f / 96, k = f - c * 96;
        union { unsigned u; _Float16 h[2]; } pk;
        pk.h[0] = (_Float16)v.x; pk.h[1] = (_Float16)v.y;
        *(unsigned*)&pwl[c * PWS + k] = pk.u;
    }
    __syncthreads();

    const int lane = tid & 63, wv = tid >> 6;
    const int lg = lane >> 4, lc = lane & 15;
    const int b  = blockIdx.y;
    const int p0 = blockIdx.x * 256 + wv * 64;   // wave's 64-pixel strip
    const _Float16* yb = y3 + (size_t)b * C_ * HW_;

    f32x4 acc[6][4];
#pragma unroll
    for (int m = 0; m < 6; ++m)
#pragma unroll
        for (int n = 0; n < 4; ++n) acc[m][n] = (f32x4){0.f, 0.f, 0.f, 0.f};

#pragma unroll
    for (int ks = 0; ks < 3; ++ks) {
        f16x8 af[6];
#pragma unroll
        for (int m = 0; m < 6; ++m)
            af[m] = *(const f16x8*)&pwl[(m * 16 + lc) * PWS + ks * 32 + lg * 8];
#pragma unroll
        for (int nf = 0; nf < 4; ++nf) {
            union { f16x8 v; _Float16 e[8]; } bf;
            const _Float16* yp = yb + (size_t)(ks * 32 + lg * 8) * HW_ + p0 + nf * 16 + lc;
#pragma unroll
            for (int j = 0; j < 8; ++j) bf.e[j] = yp[(size_t)j * HW_];
#pragma unroll
            for (int m = 0; m < 6; ++m)
                acc[m][nf] = __builtin_amdgcn_mfma_f32_16x16x32_f16(af[m], bf.v, acc[m][nf], 0, 0, 0);
        }
    }

    // epilogue: gate with x recomputed exactly in fp32
    float2 st[4];
#pragma unroll
    for (int nf = 0; nf < 4; ++nf)
        st[nf] = stats[(size_t)b * HW_ + p0 + nf * 16 + lc];

#pragma unroll
    for (int m = 0; m < 6; ++m) {
#pragma unroll
        for (int r = 0; r < 4; ++r) {
            int c = m * 16 + lg * 4 + r;
            float gm = gamma[c], btv = beta[c];
            const float* fp = fea + ((size_t)b * C_ + c) * HW_ + p0 + lc;
            float*       op = out + ((size_t)b * C_ + c) * HW_ + p0 + lc;
#pragma unroll
            for (int nf = 0; nf < 4; ++nf) {
                float xv = (fp[nf * 16] - st[nf].x) * st[nf].y * gm + btv;
                op[nf * 16] = acc[m][nf][r] * xv;
            }
        }
    }
}

extern "C" void kernel_launch(void* const* d_in, const int* in_sizes, int n_in,
                              void* d_out, int out_size, void* d_ws, size_t ws_size,
                              hipStream_t stream) {
    const float* fea   = (const float*)d_in[0];
    const float* gamma = (const float*)d_in[1];
    const float* beta  = (const float*)d_in[2];
    const float* w1    = (const float*)d_in[3];
    const float* b1    = (const float*)d_in[4];
    const float* w2    = (const float*)d_in[5];
    const float* b2    = (const float*)d_in[6];
    const float* w3    = (const float*)d_in[7];
    const float* b3    = (const float*)d_in[8];
    const float* pw    = (const float*)d_in[9];
    float* out = (float*)d_out;

    _Float16* y3buf = (_Float16*)d_ws;                                    // 100.66 MB
    float*    statp = (float*)((char*)d_ws + (size_t)B_ * C_ * HW_ * 2);  // +4.19 MB

    k_stats<<<dim3(B_ * HW_ / 512), 256, 0, stream>>>(fea, (float4*)statp);
    k_dw<<<dim3(W_ / 64, H_ / 64, C_ * B_), 256, 0, stream>>>(
        fea, (const float2*)statp, gamma, beta, w1, b1, w2, b2, w3, b3, y3buf);
    k_pw<<<dim3(HW_ / 256, B_), 256, 0, stream>>>(
        y3buf, fea, (const float2*)statp, gamma, beta, pw, out);
}

// Round 4
// 598.823 us; speedup vs baseline: 2.0883x; 1.3126x over previous
//
#include <hip/hip_runtime.h>
#include <hip/hip_bf16.h>

#define B_ 8
#define C_ 96
#define H_ 256
#define W_ 256
#define HW_ (H_*W_)
#define EPSV 1e-5f

typedef _Float16 f16x8 __attribute__((ext_vector_type(8)));
typedef float    f32x4 __attribute__((ext_vector_type(4)));

// ---------------------------------------------------------------------------
// K1: per-pixel LN stats, 2 pixels/thread via float2 loads.
// ---------------------------------------------------------------------------
__global__ __launch_bounds__(256) void k_stats(const float* __restrict__ fea,
                                               float4* __restrict__ stats4) {
    int p2 = blockIdx.x * 256 + threadIdx.x;
    int b  = p2 >> 15;
    int r  = (p2 & 32767) * 2;
    const float* pp = fea + (size_t)b * C_ * HW_ + r;
    float s0 = 0.f, q0 = 0.f, s1 = 0.f, q1 = 0.f;
#pragma unroll 8
    for (int c = 0; c < C_; ++c) {
        float2 v = *(const float2*)(pp + (size_t)c * HW_);
        s0 += v.x; q0 += v.x * v.x;
        s1 += v.y; q1 += v.y * v.y;
    }
    float mu0 = s0 * (1.0f / C_), mu1 = s1 * (1.0f / C_);
    float rs0 = rsqrtf(q0 * (1.0f / C_) - mu0 * mu0 + EPSV);
    float rs1 = rsqrtf(q1 * (1.0f / C_) - mu1 * mu1 + EPSV);
    stats4[p2] = make_float4(mu0, rs0, mu1, rs1);
}

// ---------------------------------------------------------------------------
// K2: block = (32x32 tile, 8-channel group). Fused LN + (3x3·1x5) + 5x1.
// LDS stride 44 (== 12 mod 32 -> uniform bank load on b128 windows).
// y3 written pixel-major: [b][cg][hw][8ch] fp16, coalesced uint4 stores.
// ---------------------------------------------------------------------------
#define XSTR 44

__global__ __launch_bounds__(256) void k_dw(
    const float* __restrict__ fea, const float2* __restrict__ stats,
    const float* __restrict__ gamma, const float* __restrict__ beta,
    const float* __restrict__ w1, const float* __restrict__ b1,
    const float* __restrict__ w2, const float* __restrict__ b2,
    const float* __restrict__ w3, const float* __restrict__ b3,
    _Float16* __restrict__ y3g)
{
    __shared__ __align__(16) float     xs [38 * XSTR];  // x  rows 0..37 = gh-3..+34, cols 0..37
    __shared__ __align__(16) float     y2b[36 * XSTR];  // y2 rows 0..35 = gh-2..+33, cols 0..31
    __shared__ __align__(16) _Float16  y3p[8][1032];    // per-channel 32x32 planes

    const int tid = threadIdx.x;
    const int bw0 = blockIdx.x * 32;
    const int bh0 = blockIdx.y * 32;
    const int z   = blockIdx.z;
    const int b   = z / 12;
    const int cg  = z % 12;
    const float2* stb = stats + (size_t)b * HW_;

    // ---- stage channel j: xs = LN(fea) over 38x38 halo (0 outside image)
    auto STAGE = [&](int j) {
        int c = cg * 8 + j;
        float g = gamma[c], bt = beta[c];
        const float* feac = fea + ((size_t)b * C_ + c) * HW_;
#pragma unroll 1
        for (int p = tid; p < 38 * 38; p += 256) {
            int r = p / 38, cc = p - 38 * (p / 38);
            int gh = bh0 - 3 + r, gw = bw0 - 3 + cc;
            float v = 0.f;
            if ((unsigned)gh < H_ && (unsigned)gw < W_) {
                float2 st = stb[(gh << 8) + gw];
                v = (feac[(gh << 8) + gw] - st.x) * st.y * g + bt;
            }
            xs[r * XSTR + cc] = v;
        }
    };

    STAGE(0);
    __syncthreads();

#pragma unroll 1
    for (int j = 0; j < 8; ++j) {
        const int c = cg * 8 + j;

        // ---- fused conv1(3x3)+conv2(1x5): 36 rows x 4 groups of 8 cols
        if (tid < 144) {
            float w1v[9], w2v[5];
#pragma unroll
            for (int i = 0; i < 9; ++i) w1v[i] = w1[c * 9 + i];
#pragma unroll
            for (int i = 0; i < 5; ++i) w2v[i] = w2[c * 5 + i];
            const float bb1 = b1[c], bb2 = b2[c];

            int ry = tid >> 2, g4 = tid & 3;     // y2 row 0..35, col base 8*g4
            int cb = 8 * g4;
            float wnd[3][16];
#pragma unroll
            for (int dr = 0; dr < 3; ++dr) {
                const float* rp = &xs[(ry + dr) * XSTR + cb];
                float4 a = *(const float4*)(rp + 0);
                float4 e = *(const float4*)(rp + 4);
                float4 f = *(const float4*)(rp + 8);
                float4 d = *(const float4*)(rp + 12);
                wnd[dr][0]=a.x;  wnd[dr][1]=a.y;  wnd[dr][2]=a.z;  wnd[dr][3]=a.w;
                wnd[dr][4]=e.x;  wnd[dr][5]=e.y;  wnd[dr][6]=e.z;  wnd[dr][7]=e.w;
                wnd[dr][8]=f.x;  wnd[dr][9]=f.y;  wnd[dr][10]=f.z; wnd[dr][11]=f.w;
                wnd[dr][12]=d.x; wnd[dr][13]=d.y; wnd[dr][14]=d.z; wnd[dr][15]=d.w;
            }
            int gh1 = bh0 + ry - 2;
            bool rin = (unsigned)gh1 < H_;
            float y1v[12];
#pragma unroll
            for (int k = 0; k < 12; ++k) {
                float s = bb1;
#pragma unroll
                for (int dr = 0; dr < 3; ++dr)
#pragma unroll
                    for (int dj = 0; dj < 3; ++dj)
                        s += w1v[dr * 3 + dj] * wnd[dr][k + dj];
                int gw1 = bw0 + cb - 2 + k;
                y1v[k] = (rin && (unsigned)gw1 < W_) ? s : 0.f;
            }
            float o[8];
#pragma unroll
            for (int i = 0; i < 8; ++i) {
                float s = bb2;
#pragma unroll
                for (int dj = 0; dj < 5; ++dj) s += w2v[dj] * y1v[i + dj];
                o[i] = rin ? s : 0.f;
            }
            float* yp = &y2b[ry * XSTR + cb];
            *(float4*)(yp + 0) = make_float4(o[0], o[1], o[2], o[3]);
            *(float4*)(yp + 4) = make_float4(o[4], o[5], o[6], o[7]);
        }
        __syncthreads();

        // ---- conv3 (5x1): 32 rows x 4 groups of 8 cols -> y3 plane j
        if (tid < 128) {
            float w3v[5];
#pragma unroll
            for (int i = 0; i < 5; ++i) w3v[i] = w3[c * 5 + i];
            const float bb3 = b3[c];
            int oh = tid >> 2, g4 = tid & 3;
            int cb = 8 * g4;
            float accv[8];
#pragma unroll
            for (int i = 0; i < 8; ++i) accv[i] = bb3;
#pragma unroll
            for (int dr = 0; dr < 5; ++dr) {
                const float* rp = &y2b[(oh + dr) * XSTR + cb];
                float4 a = *(const float4*)(rp + 0);
                float4 e = *(const float4*)(rp + 4);
                accv[0] += w3v[dr] * a.x; accv[1] += w3v[dr] * a.y;
                accv[2] += w3v[dr] * a.z; accv[3] += w3v[dr] * a.w;
                accv[4] += w3v[dr] * e.x; accv[5] += w3v[dr] * e.y;
                accv[6] += w3v[dr] * e.z; accv[7] += w3v[dr] * e.w;
            }
            union { uint4 q; _Float16 h[8]; } pk;
#pragma unroll
            for (int i = 0; i < 8; ++i) pk.h[i] = (_Float16)accv[i];
            *(uint4*)&y3p[j][oh * 32 + cb] = pk.q;
        }
        if (j < 7) STAGE(j + 1);
        __syncthreads();
    }

    // ---- transpose planes -> global [b][cg][hw][8], coalesced 16B stores
    _Float16* og = y3g + (size_t)(b * 12 + cg) * HW_ * 8;
#pragma unroll
    for (int i = 0; i < 4; ++i) {
        int p = i * 256 + tid;
        union { uint4 q; unsigned short h[8]; } pk;
#pragma unroll
        for (int j = 0; j < 8; ++j)
            pk.h[j] = *(const unsigned short*)&y3p[j][p];
        int oh = p >> 5, wc = p & 31;
        size_t ghw = (size_t)((bh0 + oh) << 8) + bw0 + wc;
        *(uint4*)&og[ghw * 8] = pk.q;
    }
}

// ---------------------------------------------------------------------------
// K3: pointwise 96x96 fp16 MFMA GEMM + fp32 gate. B-frags are single
// contiguous f16x8 loads from the pixel-major y3 layout.
// ---------------------------------------------------------------------------
#define PWS 104

__global__ __launch_bounds__(256) void k_pw(
    const _Float16* __restrict__ y3, const float* __restrict__ fea,
    const float2* __restrict__ stats,
    const float* __restrict__ gamma, const float* __restrict__ beta,
    const float* __restrict__ pw, float* __restrict__ out)
{
    __shared__ _Float16 pwl[C_ * PWS];
    const int tid = threadIdx.x;

#pragma unroll 1
    for (int i = 0; i < 18; ++i) {
        int f = (i * 256 + tid) * 2;
        float2 v = *(const float2*)(pw + f);
        int c = f / 96, k = f - c * 96;
        union { unsigned u; _Float16 h[2]; } pk;
        pk.h[0] = (_Float16)v.x; pk.h[1] = (_Float16)v.y;
        *(unsigned*)&pwl[c * PWS + k] = pk.u;
    }
    __syncthreads();

    const int lane = tid & 63, wv = tid >> 6;
    const int lg = lane >> 4, lc = lane & 15;
    const int b  = blockIdx.y;
    const int p0 = blockIdx.x * 256 + wv * 64;
    const _Float16* yb = y3 + (size_t)b * 12 * HW_ * 8;

    f32x4 acc[6][4];
#pragma unroll
    for (int m = 0; m < 6; ++m)
#pragma unroll
        for (int n = 0; n < 4; ++n) acc[m][n] = (f32x4){0.f, 0.f, 0.f, 0.f};

#pragma unroll
    for (int ks = 0; ks < 3; ++ks) {
        f16x8 af[6];
#pragma unroll
        for (int m = 0; m < 6; ++m)
            af[m] = *(const f16x8*)&pwl[(m * 16 + lc) * PWS + ks * 32 + lg * 8];
#pragma unroll
        for (int nf = 0; nf < 4; ++nf) {
            f16x8 bv = *(const f16x8*)&yb[((size_t)(ks * 4 + lg) * HW_ + p0 + nf * 16 + lc) * 8];
#pragma unroll
            for (int m = 0; m < 6; ++m)
                acc[m][nf] = __builtin_amdgcn_mfma_f32_16x16x32_f16(af[m], bv, acc[m][nf], 0, 0, 0);
        }
    }

    float2 st[4];
#pragma unroll
    for (int nf = 0; nf < 4; ++nf)
        st[nf] = stats[(size_t)b * HW_ + p0 + nf * 16 + lc];

#pragma unroll
    for (int m = 0; m < 6; ++m) {
#pragma unroll
        for (int r = 0; r < 4; ++r) {
            int c = m * 16 + lg * 4 + r;
            float gm = gamma[c], btv = beta[c];
            const float* fp = fea + ((size_t)b * C_ + c) * HW_ + p0 + lc;
            float*       op = out + ((size_t)b * C_ + c) * HW_ + p0 + lc;
#pragma unroll
            for (int nf = 0; nf < 4; ++nf) {
                float xv = (fp[nf * 16] - st[nf].x) * st[nf].y * gm + btv;
                op[nf * 16] = acc[m][nf][r] * xv;
            }
        }
    }
}

extern "C" void kernel_launch(void* const* d_in, const int* in_sizes, int n_in,
                              void* d_out, int out_size, void* d_ws, size_t ws_size,
                              hipStream_t stream) {
    const float* fea   = (const float*)d_in[0];
    const float* gamma = (const float*)d_in[1];
    const float* beta  = (const float*)d_in[2];
    const float* w1    = (const float*)d_in[3];
    const float* b1    = (const float*)d_in[4];
    const float* w2    = (const float*)d_in[5];
    const float* b2    = (const float*)d_in[6];
    const float* w3    = (const float*)d_in[7];
    const float* b3    = (const float*)d_in[8];
    const float* pw    = (const float*)d_in[9];
    float* out = (float*)d_out;

    _Float16* y3buf = (_Float16*)d_ws;                                    // 100.66 MB
    float*    statp = (float*)((char*)d_ws + (size_t)B_ * C_ * HW_ * 2);  // +4.19 MB

    k_stats<<<dim3(B_ * HW_ / 512), 256, 0, stream>>>(fea, (float4*)statp);
    k_dw<<<dim3(W_ / 32, H_ / 32, 12 * B_), 256, 0, stream>>>(
        fea, (const float2*)statp, gamma, beta, w1, b1, w2, b2, w3, b3, y3buf);
    k_pw<<<dim3(HW_ / 256, B_), 256, 0, stream>>>(
        y3buf, fea, (const float2*)statp, gamma, beta, pw, out);
}